// Round 5
// baseline (26251.190 us; speedup 1.0000x reference)
//
#include <hip/hip_runtime.h>
#include <hip/hip_bf16.h>
#include <hip/hip_fp16.h>

// Problem constants
#define T_STEPS 8192
#define O_DIM   1024
#define H_DIM   2048
#define G3      6144      // 3*H
#define A_DIM   512
#define NWG     256       // workgroups in scan (1 per CU)
#define SLICE   8         // hidden indices per WG
#define NROWS   24        // 3 * SLICE rows of W_hh per WG
#define RPW     3         // rows per wave (24 / 8 waves)

// X buffer rows: row t+1 holds xi[t] as fp16[6144]; hs[t] (fp32[2048]) is
// written into row t after its xi was consumed.
#define XROW_F32   3072

typedef _Float16 v2h __attribute__((ext_vector_type(2)));

__device__ __forceinline__ float dot8(uint4 w, uint4 h, float acc) {
#if defined(__has_builtin) && __has_builtin(__builtin_amdgcn_fdot2)
    acc = __builtin_amdgcn_fdot2(__builtin_bit_cast(v2h, w.x),
                                 __builtin_bit_cast(v2h, h.x), acc, false);
    acc = __builtin_amdgcn_fdot2(__builtin_bit_cast(v2h, w.y),
                                 __builtin_bit_cast(v2h, h.y), acc, false);
    acc = __builtin_amdgcn_fdot2(__builtin_bit_cast(v2h, w.z),
                                 __builtin_bit_cast(v2h, h.z), acc, false);
    acc = __builtin_amdgcn_fdot2(__builtin_bit_cast(v2h, w.w),
                                 __builtin_bit_cast(v2h, h.w), acc, false);
#else
    const __half2* wh = (const __half2*)&w;
    const __half2* hh = (const __half2*)&h;
    #pragma unroll
    for (int q = 0; q < 4; ++q) {
        float2 wf = __half22float2(wh[q]);
        float2 hf = __half22float2(hh[q]);
        acc = fmaf(wf.x, hf.x, acc);
        acc = fmaf(wf.y, hf.y, acc);
    }
#endif
    return acc;
}

// ---------------------------------------------------------------------------
// fp32 GEMM:  C[M,N] = A[M,K] @ B[N,K]^T + bias[N]
// 128x128 tile, BK=16, 256 threads, 8x8 per thread.
// OUT_HALF=1 stores C as fp16, else fp32. A row stride lda, C row stride ldc.
// ---------------------------------------------------------------------------
template <int OUT_HALF>
__global__ __launch_bounds__(256) void gemm_bt_bias(
    const float* __restrict__ A, int lda,
    const float* __restrict__ B,
    const float* __restrict__ bias,
    void* __restrict__ Cv, int ldc,
    int M, int N, int K)
{
    __shared__ float As[16][128];
    __shared__ float Bs[16][128];

    const int bm = blockIdx.y * 128;
    const int bn = blockIdx.x * 128;
    const int tid = threadIdx.x;
    const int tm = (tid >> 4) * 8;
    const int tn = (tid & 15) * 8;

    float acc[8][8] = {};

    for (int k0 = 0; k0 < K; k0 += 16) {
        #pragma unroll
        for (int u = 0; u < 2; ++u) {
            const int id = u * 256 + tid;
            const int r = id >> 2;
            const int c = (id & 3) << 2;
            float4 v = *(const float4*)(A + (size_t)(bm + r) * lda + k0 + c);
            As[c + 0][r] = v.x; As[c + 1][r] = v.y;
            As[c + 2][r] = v.z; As[c + 3][r] = v.w;
        }
        #pragma unroll
        for (int u = 0; u < 2; ++u) {
            const int id = u * 256 + tid;
            const int r = id >> 2;
            const int c = (id & 3) << 2;
            float4 v = *(const float4*)(B + (size_t)(bn + r) * K + k0 + c);
            Bs[c + 0][r] = v.x; Bs[c + 1][r] = v.y;
            Bs[c + 2][r] = v.z; Bs[c + 3][r] = v.w;
        }
        __syncthreads();

        #pragma unroll
        for (int kk = 0; kk < 16; ++kk) {
            float a[8], b[8];
            #pragma unroll
            for (int i = 0; i < 8; ++i) a[i] = As[kk][tm + i];
            #pragma unroll
            for (int j = 0; j < 8; ++j) b[j] = Bs[kk][tn + j];
            #pragma unroll
            for (int i = 0; i < 8; ++i)
                #pragma unroll
                for (int j = 0; j < 8; ++j)
                    acc[i][j] = fmaf(a[i], b[j], acc[i][j]);
        }
        __syncthreads();
    }

    if (OUT_HALF) {
        __half* C = (__half*)Cv;
        #pragma unroll
        for (int i = 0; i < 8; ++i) {
            const size_t row = (size_t)(bm + tm + i) * ldc;
            __half tmp[8];
            #pragma unroll
            for (int j = 0; j < 8; ++j)
                tmp[j] = __float2half(acc[i][j] + bias[bn + tn + j]);
            *(uint4*)(C + row + bn + tn) = *(const uint4*)tmp;
        }
    } else {
        float* C = (float*)Cv;
        #pragma unroll
        for (int i = 0; i < 8; ++i) {
            const size_t row = (size_t)(bm + tm + i) * ldc;
            #pragma unroll
            for (int j0 = 0; j0 < 8; j0 += 4) {
                const int n = bn + tn + j0;
                float4 v;
                v.x = acc[i][j0 + 0] + bias[n + 0];
                v.y = acc[i][j0 + 1] + bias[n + 1];
                v.z = acc[i][j0 + 2] + bias[n + 2];
                v.w = acc[i][j0 + 3] + bias[n + 3];
                *(float4*)(C + row + n) = v;
            }
        }
    }
}

// ---------------------------------------------------------------------------
// Persistent cooperative GRU scan, v4: fp16 weights in LDS (96 KB/CU).
// 256 WGs x 512 threads (8 waves), 1 WG/CU. WG g owns hidden idx [8g,8g+8):
// 24 rows of W_hh converted to fp16 in LDS at kernel start (no register-
// allocator dependence, no restreaming from L2).
// Cross-WG h exchange: tagged 8-byte pairs (u32 step tag | fp32 value),
// relaxed agent-scope 64-bit atomics. Owner's h kept fp32 in a register.
// Per step:
//   wave1: prefetch xi (plain cached load)
//   waves 0/2/4/6: poll own 512-pair chunk (tag>=t), stage h -> LDS (fp16)
//   sync A; all waves: 3-row dot2 matvec from LDS, butterfly -> gh_lds
//   wave1: xi -> LDS; sync B
//   wave0 lanes<8: gates (fp32, h_own register); store tagged pair + hs row
// ---------------------------------------------------------------------------
__global__ __launch_bounds__(512) void gru_scan(
    const __half*  __restrict__ xiX,     // X as fp16 rows (stride 6144)
    float*         __restrict__ hsX,     // X as fp32 rows (stride 3072)
    const float*   __restrict__ W_hh,    // [6144, 2048]
    const float*   __restrict__ b_hh,    // [6144]
    unsigned long long* __restrict__ h_pairs)  // [2, 2048] pairs, pre-zeroed
{
    const int g    = blockIdx.x;
    const int tid  = threadIdx.x;
    const int wave = tid >> 6;
    const int lane = tid & 63;

    __shared__ __align__(16) __half w_lds[NROWS][H_DIM];   // 96 KiB
    __shared__ __align__(16) __half h_lds[H_DIM];          // 4 KiB
    __shared__ float gh_lds[NROWS];
    __shared__ float bh_lds[NROWS];
    __shared__ float xi_lds[NROWS];

    // ---- preload W_hh slice -> fp16 LDS (coalesced float4 loads) ----------
    for (int l = 0; l < NROWS; ++l) {
        const int grow = (l >> 3) * H_DIM + g * SLICE + (l & 7);
        float4 v = *(const float4*)(W_hh + (size_t)grow * H_DIM + tid * 4);
        __half tmp[4] = { __float2half(v.x), __float2half(v.y),
                          __float2half(v.z), __float2half(v.w) };
        *(uint2*)(&w_lds[l][tid * 4]) = *(const uint2*)tmp;
    }
    if (tid < NROWS)
        bh_lds[tid] = b_hh[(tid >> 3) * H_DIM + g * SLICE + (tid & 7)];
    __syncthreads();

    float h_own = 0.f;   // wave0 lanes<8: own fp32 hidden value

    for (int t = 0; t < T_STEPS; ++t) {
        // wave1: prefetch xi for this step (row t+1 of X), plain cached load
        float xpre = 0.f;
        if (wave == 1 && lane < NROWS)
            xpre = __half2float(
                xiX[(size_t)(t + 1) * G3 + (lane >> 3) * H_DIM + g * SLICE + (lane & 7)]);

        // waves 0/2/4/6: poll own chunk of tagged pairs, stage h (fp16) -> LDS
        if ((wave & 1) == 0) {
            const int chunk = wave >> 1;                       // 0..3
            const unsigned long long* pp =
                h_pairs + (size_t)(t & 1) * H_DIM + chunk * 512 + lane;
            unsigned long long p[8];
            for (;;) {
                #pragma unroll
                for (int m = 0; m < 8; ++m)
                    p[m] = __hip_atomic_load(pp + m * 64, __ATOMIC_RELAXED,
                                             __HIP_MEMORY_SCOPE_AGENT);
                bool ok = true;
                #pragma unroll
                for (int m = 0; m < 8; ++m)
                    ok &= ((unsigned)(p[m] >> 32) >= (unsigned)t);
                if (__all(ok)) break;
                __builtin_amdgcn_s_sleep(1);
            }
            #pragma unroll
            for (int m = 0; m < 8; ++m)
                h_lds[chunk * 512 + lane + m * 64] =
                    __float2half(__uint_as_float((unsigned)p[m]));
        }
        __syncthreads();   // A: h_lds ready

        // all waves: 3-row dot2 matvec from LDS
        // lane's k-set: { j*512 + lane*8 + 0..7, j=0..3 }  (conflict-free)
        uint4 hv[4];
        #pragma unroll
        for (int j = 0; j < 4; ++j)
            hv[j] = *(const uint4*)(&h_lds[j * 512 + lane * 8]);

        const int l0 = wave * RPW;
        float acc[RPW] = {0.f, 0.f, 0.f};
        #pragma unroll
        for (int r = 0; r < RPW; ++r) {
            #pragma unroll
            for (int j = 0; j < 4; ++j) {
                uint4 wv = *(const uint4*)(&w_lds[l0 + r][j * 512 + lane * 8]);
                acc[r] = dot8(wv, hv[j], acc[r]);
            }
        }

        #pragma unroll
        for (int r = 0; r < RPW; ++r) {
            float a = acc[r];
            #pragma unroll
            for (int off = 32; off >= 1; off >>= 1)
                a += __shfl_xor(a, off, 64);
            if (lane == 0) gh_lds[l0 + r] = a;
        }
        if (wave == 1 && lane < NROWS) xi_lds[lane] = xpre;
        __syncthreads();   // B: gh_lds + xi_lds ready

        if (wave == 0 && lane < SLICE) {
            const int i = g * SLICE + lane;
            const float ghr = gh_lds[lane]      + bh_lds[lane];
            const float ghz = gh_lds[8 + lane]  + bh_lds[8 + lane];
            const float ghn = gh_lds[16 + lane] + bh_lds[16 + lane];
            const float xr = xi_lds[lane];
            const float xz = xi_lds[8 + lane];
            const float xn = xi_lds[16 + lane];
            const float rg = 1.f / (1.f + __expf(-(xr + ghr)));
            const float zg = 1.f / (1.f + __expf(-(xz + ghz)));
            const float ng = tanhf(xn + rg * ghn);
            const float hnew = (1.f - zg) * ng + zg * h_own;
            h_own = hnew;
            const unsigned long long pr =
                ((unsigned long long)(unsigned)(t + 1) << 32) |
                (unsigned long long)__float_as_uint(hnew);
            __hip_atomic_store(h_pairs + (size_t)((t + 1) & 1) * H_DIM + i, pr,
                               __ATOMIC_RELAXED, __HIP_MEMORY_SCOPE_AGENT);
            hsX[(size_t)t * XROW_F32 + i] = hnew;   // read after kernel end
        }
        // no third sync: next step's sync A protects the LDS buffers; the
        // chunk containing this WG's own pairs cannot pass its poll until
        // the stores above are visible.
    }
}

// ---------------------------------------------------------------------------
extern "C" void kernel_launch(void* const* d_in, const int* in_sizes, int n_in,
                              void* d_out, int out_size, void* d_ws, size_t ws_size,
                              hipStream_t stream) {
    const float* obs  = (const float*)d_in[0];
    const float* W_ih = (const float*)d_in[1];
    const float* W_hh = (const float*)d_in[2];
    const float* b_ih = (const float*)d_in[3];
    const float* b_hh = (const float*)d_in[4];
    const float* W_o  = (const float*)d_in[5];
    const float* b_o  = (const float*)d_in[6];
    const float* W_d  = (const float*)d_in[7];
    const float* b_d  = (const float*)d_in[8];
    float* out = (float*)d_out;

    // Workspace layout (~100.8 MiB total):
    //   [4096, 36864)   h tagged pairs (2 x 2048 x 8 B), pre-zeroed
    //   [65536, ...)    X buffer: (T+1) rows x 12288 B
    char*  ws = (char*)d_ws;
    unsigned long long* h_pairs = (unsigned long long*)(ws + 4096);
    char*   X   = ws + 65536;
    __half* xiX = (__half*)X;   // fp16 rows, stride 6144
    float*  hsX = (float*)X;    // fp32 rows, stride 3072

    hipMemsetAsync(d_ws, 0, 65536, stream);

    // Phase 1: xi[t] = obs @ W_ih.T + b_ih  -> fp16 into X row t+1
    gemm_bt_bias<1><<<dim3(G3 / 128, T_STEPS / 128), 256, 0, stream>>>(
        obs, O_DIM, W_ih, b_ih, (void*)(xiX + G3), G3, T_STEPS, G3, O_DIM);

    // Phase 2: sequential GRU scan (cooperative, 256 WGs x 512 threads)
    {
        void* args[] = { (void*)&xiX, (void*)&hsX, (void*)&W_hh, (void*)&b_hh,
                         (void*)&h_pairs };
        hipLaunchCooperativeKernel((const void*)gru_scan,
                                   dim3(NWG), dim3(512), args, 0, stream);
    }

    // Phase 3: output projections (A = hs rows inside X, lda = 3072)
    gemm_bt_bias<0><<<dim3(A_DIM / 128, T_STEPS / 128), 256, 0, stream>>>(
        (const float*)hsX, XROW_F32, W_o, b_o, (void*)out, A_DIM,
        T_STEPS, A_DIM, H_DIM);
    gemm_bt_bias<0><<<dim3(A_DIM / 128, T_STEPS / 128), 256, 0, stream>>>(
        (const float*)hsX, XROW_F32, W_d, b_d,
        (void*)(out + (size_t)T_STEPS * A_DIM), A_DIM,
        T_STEPS, A_DIM, H_DIM);
}

// Round 6
// 17839.218 us; speedup vs baseline: 1.4715x; 1.4715x over previous
//
#include <hip/hip_runtime.h>
#include <hip/hip_bf16.h>
#include <hip/hip_fp16.h>

// Problem constants
#define T_STEPS 8192
#define O_DIM   1024
#define H_DIM   2048
#define G3      6144      // 3*H
#define A_DIM   512
#define NWG     256       // workgroups in scan (1 per CU)
#define SLICE   8         // hidden indices per WG (= waves per WG)
#define NROWS   24        // 3 * SLICE rows of W_hh per WG
#define RPW     3         // rows per wave (r, z, n gate rows of own idx)

// X buffer rows: row t+1 holds xi[t] as fp16[6144]; hs[t] (fp32[2048]) is
// written into row t after its xi was consumed.
#define XROW_F32   3072

typedef _Float16 v2h __attribute__((ext_vector_type(2)));

__device__ __forceinline__ float dot8(uint4 w, uint4 h, float acc) {
#if defined(__has_builtin) && __has_builtin(__builtin_amdgcn_fdot2)
    acc = __builtin_amdgcn_fdot2(__builtin_bit_cast(v2h, w.x),
                                 __builtin_bit_cast(v2h, h.x), acc, false);
    acc = __builtin_amdgcn_fdot2(__builtin_bit_cast(v2h, w.y),
                                 __builtin_bit_cast(v2h, h.y), acc, false);
    acc = __builtin_amdgcn_fdot2(__builtin_bit_cast(v2h, w.z),
                                 __builtin_bit_cast(v2h, h.z), acc, false);
    acc = __builtin_amdgcn_fdot2(__builtin_bit_cast(v2h, w.w),
                                 __builtin_bit_cast(v2h, h.w), acc, false);
#else
    const __half2* wh = (const __half2*)&w;
    const __half2* hh = (const __half2*)&h;
    #pragma unroll
    for (int q = 0; q < 4; ++q) {
        float2 wf = __half22float2(wh[q]);
        float2 hf = __half22float2(hh[q]);
        acc = fmaf(wf.x, hf.x, acc);
        acc = fmaf(wf.y, hf.y, acc);
    }
#endif
    return acc;
}

// ---------------------------------------------------------------------------
// fp32 GEMM:  C[M,N] = A[M,K] @ B[N,K]^T + bias[N]
// 128x128 tile, BK=16, 256 threads, 8x8 per thread.
// OUT_HALF=1 stores C as fp16, else fp32. A row stride lda, C row stride ldc.
// ---------------------------------------------------------------------------
template <int OUT_HALF>
__global__ __launch_bounds__(256) void gemm_bt_bias(
    const float* __restrict__ A, int lda,
    const float* __restrict__ B,
    const float* __restrict__ bias,
    void* __restrict__ Cv, int ldc,
    int M, int N, int K)
{
    __shared__ float As[16][128];
    __shared__ float Bs[16][128];

    const int bm = blockIdx.y * 128;
    const int bn = blockIdx.x * 128;
    const int tid = threadIdx.x;
    const int tm = (tid >> 4) * 8;
    const int tn = (tid & 15) * 8;

    float acc[8][8] = {};

    for (int k0 = 0; k0 < K; k0 += 16) {
        #pragma unroll
        for (int u = 0; u < 2; ++u) {
            const int id = u * 256 + tid;
            const int r = id >> 2;
            const int c = (id & 3) << 2;
            float4 v = *(const float4*)(A + (size_t)(bm + r) * lda + k0 + c);
            As[c + 0][r] = v.x; As[c + 1][r] = v.y;
            As[c + 2][r] = v.z; As[c + 3][r] = v.w;
        }
        #pragma unroll
        for (int u = 0; u < 2; ++u) {
            const int id = u * 256 + tid;
            const int r = id >> 2;
            const int c = (id & 3) << 2;
            float4 v = *(const float4*)(B + (size_t)(bn + r) * K + k0 + c);
            Bs[c + 0][r] = v.x; Bs[c + 1][r] = v.y;
            Bs[c + 2][r] = v.z; Bs[c + 3][r] = v.w;
        }
        __syncthreads();

        #pragma unroll
        for (int kk = 0; kk < 16; ++kk) {
            float a[8], b[8];
            #pragma unroll
            for (int i = 0; i < 8; ++i) a[i] = As[kk][tm + i];
            #pragma unroll
            for (int j = 0; j < 8; ++j) b[j] = Bs[kk][tn + j];
            #pragma unroll
            for (int i = 0; i < 8; ++i)
                #pragma unroll
                for (int j = 0; j < 8; ++j)
                    acc[i][j] = fmaf(a[i], b[j], acc[i][j]);
        }
        __syncthreads();
    }

    if (OUT_HALF) {
        __half* C = (__half*)Cv;
        #pragma unroll
        for (int i = 0; i < 8; ++i) {
            const size_t row = (size_t)(bm + tm + i) * ldc;
            __half tmp[8];
            #pragma unroll
            for (int j = 0; j < 8; ++j)
                tmp[j] = __float2half(acc[i][j] + bias[bn + tn + j]);
            *(uint4*)(C + row + bn + tn) = *(const uint4*)tmp;
        }
    } else {
        float* C = (float*)Cv;
        #pragma unroll
        for (int i = 0; i < 8; ++i) {
            const size_t row = (size_t)(bm + tm + i) * ldc;
            #pragma unroll
            for (int j0 = 0; j0 < 8; j0 += 4) {
                const int n = bn + tn + j0;
                float4 v;
                v.x = acc[i][j0 + 0] + bias[n + 0];
                v.y = acc[i][j0 + 1] + bias[n + 1];
                v.z = acc[i][j0 + 2] + bias[n + 2];
                v.w = acc[i][j0 + 3] + bias[n + 3];
                *(float4*)(C + row + n) = v;
            }
        }
    }
}

// ---------------------------------------------------------------------------
// Persistent cooperative GRU scan, v5: minimum-latency step pipeline.
// 256 WGs x 512 threads (8 waves). Wave w of WG g owns hidden idx i=8g+w,
// i.e. W_hh rows {w, 8+w, 16+w} (fp16, LDS-resident, 96 KiB).
// h exchange: 4-B packets (tag<<16 | fp16 value), relaxed agent atomics,
// ping-pong [2][2048]. One __syncthreads per step; h_lds double-buffered.
// Safety invariants:
//  - A packet in buf b can only be overwritten with tag t+2 after ALL WGs
//    stored tag t+1, which happens after their poll of tag t on buf b ->
//    no consumer can read a too-new value.
//  - h_lds[t&1] is re-written only at step t+2, which is after barrier(t+1),
//    which certifies all waves finished matvec(t) reads.
// Per step (per wave): prefetch xi (lane0) -> issue 12 weight ds_reads ->
// poll own 256-packet chunk -> stage bits into h_lds -> barrier -> h ds_read
// -> 48 fdot2 -> butterfly -> lane0 gates -> 4-B packet store + hs store.
// ---------------------------------------------------------------------------
__global__ __launch_bounds__(512) void gru_scan(
    const __half*  __restrict__ xiX,     // X as fp16 rows (stride 6144)
    float*         __restrict__ hsX,     // X as fp32 rows (stride 3072)
    const float*   __restrict__ W_hh,    // [6144, 2048]
    const float*   __restrict__ b_hh,    // [6144]
    unsigned*      __restrict__ pairs)   // [2][2048] packets, pre-zeroed
{
    const int g    = blockIdx.x;
    const int tid  = threadIdx.x;
    const int wave = tid >> 6;
    const int lane = tid & 63;
    const int my_i = g * SLICE + wave;   // hidden index owned by this wave

    __shared__ __align__(16) __half w_lds[NROWS][H_DIM];   // 96 KiB
    __shared__ __align__(16) __half h_lds[2][H_DIM];       // 8 KiB

    // ---- preload W_hh slice -> fp16 LDS (coalesced float4 loads) ----------
    for (int l = 0; l < NROWS; ++l) {
        const int grow = (l >> 3) * H_DIM + g * SLICE + (l & 7);
        float4 v = *(const float4*)(W_hh + (size_t)grow * H_DIM + tid * 4);
        __half tmp[4] = { __float2half(v.x), __float2half(v.y),
                          __float2half(v.z), __float2half(v.w) };
        *(uint2*)(&w_lds[l][tid * 4]) = *(const uint2*)tmp;
    }
    float bh_r = 0.f, bh_z = 0.f, bh_n = 0.f;
    if (lane == 0) {
        bh_r = b_hh[my_i];
        bh_z = b_hh[H_DIM + my_i];
        bh_n = b_hh[2 * H_DIM + my_i];
    }
    __syncthreads();

    float h_own = 0.f;   // lane0: fp32 hidden value of own index

    for (int t = 0; t < T_STEPS; ++t) {
        // lane0: prefetch xi for this step (row t+1 of X), plain cached loads
        float xr = 0.f, xz = 0.f, xn = 0.f;
        if (lane == 0) {
            const __half* xp = xiX + (size_t)(t + 1) * G3 + my_i;
            xr = __half2float(xp[0]);
            xz = __half2float(xp[H_DIM]);
            xn = __half2float(xp[2 * H_DIM]);
        }

        // issue weight ds_reads now: LDS port works during the poll wait
        uint4 wv[RPW][4];
        #pragma unroll
        for (int r = 0; r < RPW; ++r)
            #pragma unroll
            for (int j = 0; j < 4; ++j)
                wv[r][j] = *(const uint4*)(&w_lds[r * 8 + wave][j * 512 + lane * 8]);

        // poll own chunk of 256 packets (4/lane), stage bits into h_lds[t&1]
        {
            const unsigned long long* pp = (const unsigned long long*)
                (pairs + (size_t)(t & 1) * H_DIM + wave * 256 + lane * 4);
            const unsigned tgt = (unsigned)t;
            unsigned long long p0, p1;
            for (;;) {
                p0 = __hip_atomic_load(pp + 0, __ATOMIC_RELAXED,
                                       __HIP_MEMORY_SCOPE_AGENT);
                p1 = __hip_atomic_load(pp + 1, __ATOMIC_RELAXED,
                                       __HIP_MEMORY_SCOPE_AGENT);
                bool ok = (((unsigned)(p0 >> 16) & 0xFFFFu) >= tgt) &&
                          (((unsigned)(p0 >> 48))           >= tgt) &&
                          (((unsigned)(p1 >> 16) & 0xFFFFu) >= tgt) &&
                          (((unsigned)(p1 >> 48))           >= tgt);
                if (__all(ok)) break;
                __builtin_amdgcn_s_sleep(1);
            }
            const unsigned long long hbits =
                  (p0 & 0xFFFFull)
                | ((p0 >> 32) & 0xFFFFull) << 16
                | ((p1 & 0xFFFFull) << 32)
                | ((p1 >> 32) & 0xFFFFull) << 48;
            *(unsigned long long*)(&h_lds[t & 1][wave * 256 + lane * 4]) = hbits;
        }
        __syncthreads();   // h_lds[t&1] ready

        // matvec: 3 rows x 2048 via fp16 dot2, fp32 accumulate
        uint4 hv[4];
        #pragma unroll
        for (int j = 0; j < 4; ++j)
            hv[j] = *(const uint4*)(&h_lds[t & 1][j * 512 + lane * 8]);

        float acc[RPW] = {0.f, 0.f, 0.f};
        #pragma unroll
        for (int r = 0; r < RPW; ++r)
            #pragma unroll
            for (int j = 0; j < 4; ++j)
                acc[r] = dot8(wv[r][j], hv[j], acc[r]);

        // butterfly reduce each row across 64 lanes
        #pragma unroll
        for (int r = 0; r < RPW; ++r) {
            float a = acc[r];
            #pragma unroll
            for (int off = 32; off >= 1; off >>= 1)
                a += __shfl_xor(a, off, 64);
            acc[r] = a;
        }

        // lane0: gates + publish
        if (lane == 0) {
            const float ghr = acc[0] + bh_r;
            const float ghz = acc[1] + bh_z;
            const float ghn = acc[2] + bh_n;
            const float rg = 1.f / (1.f + __expf(-(xr + ghr)));
            const float zg = 1.f / (1.f + __expf(-(xz + ghz)));
            float a = xn + rg * ghn;
            a = fminf(fmaxf(a, -15.f), 15.f);
            const float e2 = __expf(-2.f * a);
            const float ng = (1.f - e2) / (1.f + e2);   // tanh(a)
            const float hnew = (1.f - zg) * ng + zg * h_own;
            h_own = hnew;
            const unsigned pr = ((unsigned)(t + 1) << 16) |
                (unsigned)__half_as_ushort(__float2half(hnew));
            __hip_atomic_store(pairs + (size_t)((t + 1) & 1) * H_DIM + my_i, pr,
                               __ATOMIC_RELAXED, __HIP_MEMORY_SCOPE_AGENT);
            hsX[(size_t)t * XROW_F32 + my_i] = hnew;   // read after kernel end
        }
    }
}

// ---------------------------------------------------------------------------
extern "C" void kernel_launch(void* const* d_in, const int* in_sizes, int n_in,
                              void* d_out, int out_size, void* d_ws, size_t ws_size,
                              hipStream_t stream) {
    const float* obs  = (const float*)d_in[0];
    const float* W_ih = (const float*)d_in[1];
    const float* W_hh = (const float*)d_in[2];
    const float* b_ih = (const float*)d_in[3];
    const float* b_hh = (const float*)d_in[4];
    const float* W_o  = (const float*)d_in[5];
    const float* b_o  = (const float*)d_in[6];
    const float* W_d  = (const float*)d_in[7];
    const float* b_d  = (const float*)d_in[8];
    float* out = (float*)d_out;

    // Workspace layout (~100.8 MiB total):
    //   [4096, 20480)   h packets (2 x 2048 x 4 B), pre-zeroed
    //   [65536, ...)    X buffer: (T+1) rows x 12288 B
    char*     ws    = (char*)d_ws;
    unsigned* pairs = (unsigned*)(ws + 4096);
    char*     X     = ws + 65536;
    __half*   xiX   = (__half*)X;   // fp16 rows, stride 6144
    float*    hsX   = (float*)X;    // fp32 rows, stride 3072

    hipMemsetAsync(d_ws, 0, 65536, stream);

    // Phase 1: xi[t] = obs @ W_ih.T + b_ih  -> fp16 into X row t+1
    gemm_bt_bias<1><<<dim3(G3 / 128, T_STEPS / 128), 256, 0, stream>>>(
        obs, O_DIM, W_ih, b_ih, (void*)(xiX + G3), G3, T_STEPS, G3, O_DIM);

    // Phase 2: sequential GRU scan (cooperative, 256 WGs x 512 threads)
    {
        void* args[] = { (void*)&xiX, (void*)&hsX, (void*)&W_hh, (void*)&b_hh,
                         (void*)&pairs };
        hipLaunchCooperativeKernel((const void*)gru_scan,
                                   dim3(NWG), dim3(512), args, 0, stream);
    }

    // Phase 3: output projections (A = hs rows inside X, lda = 3072)
    gemm_bt_bias<0><<<dim3(A_DIM / 128, T_STEPS / 128), 256, 0, stream>>>(
        (const float*)hsX, XROW_F32, W_o, b_o, (void*)out, A_DIM,
        T_STEPS, A_DIM, H_DIM);
    gemm_bt_bias<0><<<dim3(A_DIM / 128, T_STEPS / 128), 256, 0, stream>>>(
        (const float*)hsX, XROW_F32, W_d, b_d,
        (void*)(out + (size_t)T_STEPS * A_DIM), A_DIM,
        T_STEPS, A_DIM, H_DIM);
}